// Round 4
// baseline (2105.985 us; speedup 1.0000x reference)
//
#include <hip/hip_runtime.h>

// SimpleRNN: h_{t+1} = tanh(h Wh^T + x_t Wx^T + b), return h_1024.
// SEQ=1024, NB=64, HID=512, IN=512. W is [512][1024] = [Wh | Wx]. All fp32 I/O.
//
// Phase 1 (prepass): U[t][b][j] = x_t[b]·Wx[j] + b[j] as MFMA f16 GEMM, U f16 in ws.
// Phase 2 (recurrent): 256 WGs = 32 batch-PAIRS x 8 row-slices (64 rows each).
//   B=2: each WG's 64x512 Wh slice (64 KB f16 LDS, thread-order chunks) is
//   register-reused across both batches -> per-step weight LDS traffic halves
//   vs R3's B=1 (R3: 128KB/step, LDS-port-bound at 0.75us/step of 1.32).
// Sync: h published as atomic u64 {tag, 2xf16} parity ping-pong (proven R3).

#define SEQ 1024
#define NB  64
#define HID 512

typedef _Float16 half2v __attribute__((ext_vector_type(2)));
typedef _Float16 f16x8  __attribute__((ext_vector_type(8)));
typedef float    f32x4  __attribute__((ext_vector_type(4)));

#if __has_builtin(__builtin_amdgcn_fdot2)
#define DOT2(a, b, c) __builtin_amdgcn_fdot2((a), (b), (c), false)
#else
static __device__ __forceinline__ float DOT2(half2v a, half2v b, float c) {
  return c + (float)a.x * (float)b.x + (float)a.y * (float)b.y;
}
#endif

static __device__ __forceinline__ float fast_tanh(float x) {
  float e = __expf(2.0f * x);
  return (e - 1.0f) / (e + 1.0f);
}

// ---------------------------------------------------------------- prepass ---
__global__ __launch_bounds__(256, 2)
void rnn_prepass(const float* __restrict__ X, const float* __restrict__ W,
                 const float* __restrict__ bias, _Float16* __restrict__ U) {
  __shared__ __align__(16) _Float16 As[128][40];
  __shared__ __align__(16) _Float16 Bs[128][40];
  const int tid = threadIdx.x;
  const int m0 = blockIdx.x * 128;
  const int n0 = blockIdx.y * 128;
  const int wave = tid >> 6, lane = tid & 63;
  const int wm = (wave >> 1) * 64, wn = (wave & 1) * 64;
  const int l15 = lane & 15, q = lane >> 4;

  f32x4 acc[4][4];
#pragma unroll
  for (int i = 0; i < 4; ++i)
#pragma unroll
    for (int j = 0; j < 4; ++j) acc[i][j] = (f32x4){0.f, 0.f, 0.f, 0.f};

  const int srow = tid >> 1;
  const int shalf = (tid & 1) * 16;

  for (int k0 = 0; k0 < 512; k0 += 32) {
    const float* asrc = X + (size_t)(m0 + srow) * 512 + k0 + shalf;
    const float* bsrc = W + (size_t)(n0 + srow) * 1024 + 512 + k0 + shalf;
    float4 a0 = *(const float4*)(asrc);
    float4 a1 = *(const float4*)(asrc + 4);
    float4 a2 = *(const float4*)(asrc + 8);
    float4 a3 = *(const float4*)(asrc + 12);
    float4 b0 = *(const float4*)(bsrc);
    float4 b1 = *(const float4*)(bsrc + 4);
    float4 b2 = *(const float4*)(bsrc + 8);
    float4 b3 = *(const float4*)(bsrc + 12);
    __syncthreads();
    f16x8 pa0 = {(_Float16)a0.x, (_Float16)a0.y, (_Float16)a0.z, (_Float16)a0.w,
                 (_Float16)a1.x, (_Float16)a1.y, (_Float16)a1.z, (_Float16)a1.w};
    f16x8 pa1 = {(_Float16)a2.x, (_Float16)a2.y, (_Float16)a2.z, (_Float16)a2.w,
                 (_Float16)a3.x, (_Float16)a3.y, (_Float16)a3.z, (_Float16)a3.w};
    f16x8 pb0 = {(_Float16)b0.x, (_Float16)b0.y, (_Float16)b0.z, (_Float16)b0.w,
                 (_Float16)b1.x, (_Float16)b1.y, (_Float16)b1.z, (_Float16)b1.w};
    f16x8 pb1 = {(_Float16)b2.x, (_Float16)b2.y, (_Float16)b2.z, (_Float16)b2.w,
                 (_Float16)b3.x, (_Float16)b3.y, (_Float16)b3.z, (_Float16)b3.w};
    *(f16x8*)&As[srow][shalf] = pa0;
    *(f16x8*)&As[srow][shalf + 8] = pa1;
    *(f16x8*)&Bs[srow][shalf] = pb0;
    *(f16x8*)&Bs[srow][shalf + 8] = pb1;
    __syncthreads();
    f16x8 av[4], bv[4];
#pragma unroll
    for (int i = 0; i < 4; ++i)
      av[i] = *(const f16x8*)&As[wm + i * 16 + l15][q * 8];
#pragma unroll
    for (int j = 0; j < 4; ++j)
      bv[j] = *(const f16x8*)&Bs[wn + j * 16 + l15][q * 8];
#pragma unroll
    for (int i = 0; i < 4; ++i)
#pragma unroll
      for (int j = 0; j < 4; ++j)
        acc[i][j] = __builtin_amdgcn_mfma_f32_16x16x32_f16(av[i], bv[j], acc[i][j], 0, 0, 0);
  }
  float bj[4];
#pragma unroll
  for (int j = 0; j < 4; ++j) bj[j] = bias[n0 + wn + j * 16 + l15];
#pragma unroll
  for (int i = 0; i < 4; ++i)
#pragma unroll
    for (int j = 0; j < 4; ++j)
#pragma unroll
      for (int r = 0; r < 4; ++r) {
        int m = m0 + wm + i * 16 + q * 4 + r;
        int n = n0 + wn + j * 16 + l15;
        U[(size_t)m * 512 + n] = (_Float16)(acc[i][j][r] + bj[j]);
      }
}

// -------------------------------------------------------------- recurrent ---
__global__ __launch_bounds__(256, 1)
void rnn_recur(const float* __restrict__ W, const _Float16* __restrict__ U,
               unsigned long long* hbuf, float* __restrict__ out) {
  const int blk = blockIdx.x;
  const int p = blk & 31;      // batch pair: global batches {2p, 2p+1}
  const int g = blk >> 5;      // row-slice 0..7 (rows 64g..64g+63)
  const int tid = threadIdx.x;
  const int rb = tid & 15;     // row block (4 local rows: rb*4+i)
  const int kc = tid >> 4;     // k-chunk 0..15 (32 k each)

  // 64 KB weights + 2 KB h + 16.9 KB part = 83.4 KB (>80 KB: forces 1 WG/CU)
  __shared__ __align__(16) f16x8 wlds[16][256];  // [i*4+q][tid], thread-order
  __shared__ __align__(16) half2v hlds[2][256];  // h_t of both batches
  __shared__ float part[128][33];                // [b*64+row][kc], stride 33

  // One-time: 4 rows x 32 k of Wh -> f16 -> own LDS chunks (self-read only,
  // so no barrier needed beyond SYNC1).
#pragma unroll
  for (int i = 0; i < 4; ++i) {
    const float* wrow = W + (size_t)(64 * g + rb * 4 + i) * 1024 + kc * 32;
#pragma unroll
    for (int q = 0; q < 4; ++q) {
      float4 wa = *(const float4*)(wrow + 8 * q);
      float4 wb = *(const float4*)(wrow + 8 * q + 4);
      f16x8 pk = {(_Float16)wa.x, (_Float16)wa.y, (_Float16)wa.z, (_Float16)wa.w,
                  (_Float16)wb.x, (_Float16)wb.y, (_Float16)wb.z, (_Float16)wb.w};
      wlds[i * 4 + q][tid] = pk;
    }
  }

  const unsigned int* U32 = (const unsigned int*)U;
  const int rr = tid & 31, bb = tid >> 5;  // reduce-thread coords (tid<64)

  float h0f = 0.f, h1f = 0.f;
  for (int t = 0; t < SEQ; ++t) {
    // prefetch this step's U word (independent of sync)
    unsigned int ubits = 0;
    if (tid < 64)
      ubits = U32[((size_t)t * 64 + 2 * p + bb) * 256 + 32 * g + rr];

    // poll both batches' h-word for tag t (parity t&1)
    {
      const unsigned long long* s0 =
          hbuf + (size_t)(t & 1) * (NB * 256) + (size_t)(2 * p) * 256 + tid;
      const unsigned long long* s1 = s0 + 256;
      unsigned long long e0 = 0, e1 = 0;
      bool d0 = false, d1 = false;
      do {
        if (!d0) {
          e0 = __hip_atomic_load(s0, __ATOMIC_RELAXED, __HIP_MEMORY_SCOPE_AGENT);
          d0 = ((unsigned int)(e0 >> 32) == (unsigned int)t);
        }
        if (!d1) {
          e1 = __hip_atomic_load(s1, __ATOMIC_RELAXED, __HIP_MEMORY_SCOPE_AGENT);
          d1 = ((unsigned int)(e1 >> 32) == (unsigned int)t);
        }
      } while (!(d0 && d1));
      hlds[0][tid] = __builtin_bit_cast(half2v, (unsigned int)e0);
      hlds[1][tid] = __builtin_bit_cast(half2v, (unsigned int)e1);
    }
    __syncthreads();  // SYNC1: h_t staged (also fences part[] reuse)

    // 4 rows x 32 k x 2 batches per thread: 16 w-b128 + 8 h-b128 + 128 dot2
    float a00 = 0.f, a01 = 0.f, a02 = 0.f, a03 = 0.f;
    float a10 = 0.f, a11 = 0.f, a12 = 0.f, a13 = 0.f;
#pragma unroll
    for (int q = 0; q < 4; ++q) {
      f16x8 h8a = *(const f16x8*)&hlds[0][kc * 16 + q * 4];
      f16x8 h8b = *(const f16x8*)&hlds[1][kc * 16 + q * 4];
      half2v ha0 = {h8a[0], h8a[1]}, ha1 = {h8a[2], h8a[3]};
      half2v ha2 = {h8a[4], h8a[5]}, ha3 = {h8a[6], h8a[7]};
      half2v hb0 = {h8b[0], h8b[1]}, hb1 = {h8b[2], h8b[3]};
      half2v hb2 = {h8b[4], h8b[5]}, hb3 = {h8b[6], h8b[7]};
#pragma unroll
      for (int i = 0; i < 4; ++i) {
        f16x8 wv = wlds[i * 4 + q][tid];
        half2v w0 = {wv[0], wv[1]}, w1 = {wv[2], wv[3]};
        half2v w2 = {wv[4], wv[5]}, w3 = {wv[6], wv[7]};
        float* pa = (i == 0) ? &a00 : (i == 1) ? &a01 : (i == 2) ? &a02 : &a03;
        float* pb = (i == 0) ? &a10 : (i == 1) ? &a11 : (i == 2) ? &a12 : &a13;
        *pa = DOT2(w0, ha0, *pa); *pa = DOT2(w1, ha1, *pa);
        *pa = DOT2(w2, ha2, *pa); *pa = DOT2(w3, ha3, *pa);
        *pb = DOT2(w0, hb0, *pb); *pb = DOT2(w1, hb1, *pb);
        *pb = DOT2(w2, hb2, *pb); *pb = DOT2(w3, hb3, *pb);
      }
    }
    part[rb * 4 + 0][kc] = a00;
    part[rb * 4 + 1][kc] = a01;
    part[rb * 4 + 2][kc] = a02;
    part[rb * 4 + 3][kc] = a03;
    part[64 + rb * 4 + 0][kc] = a10;
    part[64 + rb * 4 + 1][kc] = a11;
    part[64 + rb * 4 + 2][kc] = a12;
    part[64 + rb * 4 + 3][kc] = a13;
    __syncthreads();  // SYNC2: partials visible

    if (tid < 64) {
      float s0 = 0.f, s1 = 0.f;
#pragma unroll
      for (int kk = 0; kk < 16; ++kk) {
        s0 += part[bb * 64 + 2 * rr][kk];
        s1 += part[bb * 64 + 2 * rr + 1][kk];
      }
      half2v uh = __builtin_bit_cast(half2v, ubits);
      h0f = fast_tanh(s0 + (float)uh.x);
      h1f = fast_tanh(s1 + (float)uh.y);
      half2v hh;
      hh.x = (_Float16)h0f;
      hh.y = (_Float16)h1f;
      unsigned long long word =
          ((unsigned long long)(unsigned int)(t + 1) << 32) |
          (unsigned long long)__builtin_bit_cast(unsigned int, hh);
      // publish rows {64g+2rr, +1} of batch 2p+bb, parity (t+1)&1.
      // Overwrite of h_{t-1} safe: observing all tag==t implies every WG of
      // this pair finished staging h_{t-1} (same argument as R3).
      __hip_atomic_store(
          hbuf + (size_t)((t + 1) & 1) * (NB * 256) +
              (size_t)(2 * p + bb) * 256 + 32 * g + rr,
          word, __ATOMIC_RELAXED, __HIP_MEMORY_SCOPE_AGENT);
    }
    // no 3rd barrier: t+1's hlds/part writes ordered behind SYNC1(t+1)/SYNC2(t)
  }
  if (tid < 64) {
    out[(size_t)(2 * p + bb) * HID + 64 * g + 2 * rr]     = h0f;
    out[(size_t)(2 * p + bb) * HID + 64 * g + 2 * rr + 1] = h1f;
  }
}

// ------------------------------------------------------------------- host ---
extern "C" void kernel_launch(void* const* d_in, const int* in_sizes, int n_in,
                              void* d_out, int out_size, void* d_ws, size_t ws_size,
                              hipStream_t stream) {
  const float* X    = (const float*)d_in[0];  // [1024][64][512]
  const float* W    = (const float*)d_in[1];  // [512][1024]
  const float* bias = (const float*)d_in[2];  // [512]
  float* out = (float*)d_out;                 // [64][512]

  // ws layout: U f16 (64 MiB) | hbuf u64[2][64][256] (256 KiB)
  char* ws = (char*)d_ws;
  _Float16* U = (_Float16*)ws;
  unsigned long long* hbuf =
      (unsigned long long*)(ws + (size_t)SEQ * NB * HID * 2);

  // parity-0 = h_0 = 0 with tag 0; parity-1 poison 0xAA.. never matches a tag
  hipMemsetAsync(hbuf, 0, (size_t)NB * 256 * 8, stream);

  rnn_prepass<<<dim3(512, 4), dim3(256), 0, stream>>>(X, W, bias, U);

  const float* Wp = W;
  const _Float16* Up = U;
  unsigned long long* hb = hbuf;
  float* op = out;
  void* args[] = {(void*)&Wp, (void*)&Up, (void*)&hb, (void*)&op};
  hipError_t e = hipLaunchCooperativeKernel(
      reinterpret_cast<void*>(rnn_recur), dim3(256), dim3(256), args, 0, stream);
  if (e != hipSuccess) {
    rnn_recur<<<dim3(256), dim3(256), 0, stream>>>(Wp, Up, hb, op);
  }
}